// Round 3
// baseline (4105.738 us; speedup 1.0000x reference)
//
#include <hip/hip_runtime.h>

#define T_SEQ 512
#define NB    256
#define NIN   248
#define NH    1024

typedef __attribute__((ext_vector_type(8))) short          short8;
typedef __attribute__((ext_vector_type(4))) float          f32x4;
typedef __attribute__((ext_vector_type(4))) unsigned int   uint4v;
typedef __attribute__((ext_vector_type(4))) float          float4v;
typedef unsigned long long u64;

#define AS_RELAXED __ATOMIC_RELAXED
#define AS_AGENT   __HIP_MEMORY_SCOPE_AGENT

__device__ __forceinline__ unsigned short f2bf(float f){
  unsigned int u = __float_as_uint(f);
  u += 0x7FFFu + ((u >> 16) & 1u);     // RNE
  return (unsigned short)(u >> 16);
}

__device__ __forceinline__ float tanh_fast(float v){
  float e = __expf(2.0f * v);          // overflow -> inf -> tanh -> 1 (safe)
  return 1.0f - 2.0f / (e + 1.0f);
}

// Persistent kernel, PLAIN launch (cooperative launch silently failed; not
// needed -- 256 blocks x 1 block/CU occupancy on 256 CUs => all co-resident;
// sync is only within 16-WG batch-groups via a monotonic spin barrier).
// Grid: 256 WGs = 16 batch-groups (bg) x 16 hidden-groups (jg).
// bg mapping keeps a batch-group's 16 WGs on ONE XCD under round-robin
// blockIdx%8 placement (locality heuristic only).
// WG tile: 16 batch rows x 64 hidden cols; 4 waves of 16x16
// mfma_f32_16x16x32_bf16; W slices resident in VGPRs for all 512 steps.
// Cross-WG h/z/barrier traffic: relaxed AGENT-scope atomics (IF$-coherent).
__launch_bounds__(256, 1)
__global__ void rnn_scan_kernel(const float* __restrict__ x,
                                const float* __restrict__ W_ih,
                                const float* __restrict__ b_ih,
                                const float* __restrict__ W_hh,
                                const float* __restrict__ b_hh,
                                const float* __restrict__ W_out,
                                unsigned short* __restrict__ hbuf,
                                float* __restrict__ z,
                                unsigned int* __restrict__ bar)
{
  __shared__ alignas(16) unsigned short h_frag[2048 * 8]; // 32 KB A-fragments
  __shared__ alignas(16) unsigned short x_frag[512 * 8];  //  8 KB x-fragments
  __shared__ alignas(8)  unsigned short h_out[16 * 64];   //  2 KB store-transpose
  __shared__ float zpart[16];

  const int tid    = threadIdx.x;
  const int wg     = blockIdx.x;
  const int r16    = wg & 15;
  const int bg     = (r16 & 7) * 2 + (r16 >> 3);  // same-XCD grouping (wg%16 fixed per bg)
  const int jg     = wg >> 4;
  const int b_base = bg * 16;
  const int l      = tid & 63;
  const int wv     = tid >> 6;
  const int n      = l & 15;     // MFMA col (B-operand n / C-D col)
  const int quad   = l >> 4;
  const int j      = jg * 64 + wv * 16 + n;   // this lane's output column

  unsigned short* h0 = hbuf;
  unsigned short* h1 = hbuf + (size_t)NB * NH;
  unsigned int* ctr  = bar + bg * 32;         // one 128B line per batch-group

  // ---- resident B fragments: W_hh^T slice (bf16) in VGPRs ----
  // B layout: lane holds B[k = quad*8 + e][n] = W_hh[j][k], 8 contiguous k.
  short8 whh[32];
  #pragma unroll
  for (int kt = 0; kt < 32; ++kt){
    const float* p = W_hh + (size_t)j * NH + kt * 32 + quad * 8;
    float4v a = *(const float4v*)p;
    float4v b = *(const float4v*)(p + 4);
    short8 v;
    v[0]=(short)f2bf(a[0]); v[1]=(short)f2bf(a[1]); v[2]=(short)f2bf(a[2]); v[3]=(short)f2bf(a[3]);
    v[4]=(short)f2bf(b[0]); v[5]=(short)f2bf(b[1]); v[6]=(short)f2bf(b[2]); v[7]=(short)f2bf(b[3]);
    whh[kt] = v;
  }
  short8 wih[8];
  #pragma unroll
  for (int kt = 0; kt < 8; ++kt){
    short8 v = {0,0,0,0,0,0,0,0};
    if (!(kt == 7 && quad == 3)){            // k in [248,256) -> zero pad
      const float* p = W_ih + (size_t)j * NIN + kt * 32 + quad * 8;
      float4v a = *(const float4v*)p;
      float4v b = *(const float4v*)(p + 4);
      v[0]=(short)f2bf(a[0]); v[1]=(short)f2bf(a[1]); v[2]=(short)f2bf(a[2]); v[3]=(short)f2bf(a[3]);
      v[4]=(short)f2bf(b[0]); v[5]=(short)f2bf(b[1]); v[6]=(short)f2bf(b[2]); v[7]=(short)f2bf(b[3]);
    }
    wih[kt] = v;
  }
  const float bias  = b_ih[j] + b_hh[j];
  const float woutj = W_out[j];

  // ---- init: h0 slice = 0, this WG's z cells = 0 (coherent stores) ----
  {
    int r = tid >> 4, c = (tid & 15) * 4;     // 16 rows x 64 cols, 8B each
    __hip_atomic_store((u64*)&h0[(size_t)(b_base + r) * NH + jg * 64 + c],
                       0ull, AS_RELAXED, AS_AGENT);
    int tt = jg * 32 + (tid >> 3);            // z[jg*32..+32][bg slice]
    int bb = (tid & 7) * 2;
    __hip_atomic_store(&z[(size_t)tt * NB + b_base + bb],     0.f, AS_RELAXED, AS_AGENT);
    __hip_atomic_store(&z[(size_t)tt * NB + b_base + bb + 1], 0.f, AS_RELAXED, AS_AGENT);
  }

  // ---- per-bg barrier (monotonic counter) ----
  unsigned int target = 16;
  __syncthreads();   // each wave drains its own stores before s_barrier
  if (tid == 0){
    __hip_atomic_fetch_add(ctr, 1u, __ATOMIC_RELEASE, AS_AGENT);
    while (__hip_atomic_load(ctr, AS_RELAXED, AS_AGENT) < target)
      __builtin_amdgcn_s_sleep(2);
  }
  __syncthreads();

  for (int t = 0; t < T_SEQ; ++t){
    const unsigned short* hp = (t & 1) ? h1 : h0;
    unsigned short*       hn = (t & 1) ? h0 : h1;

    // P1: stage h fragments (coherent 8B loads -> LDS, MFMA A layout)
    #pragma unroll
    for (int i = 0; i < 8; ++i){
      int slot = tid + i * 256;
      int kt = slot >> 6, l2 = slot & 63;
      int b = b_base + (l2 & 15), k = kt * 32 + (l2 >> 4) * 8;
      const u64* src = (const u64*)(hp + (size_t)b * NH + k);
      u64 w0 = __hip_atomic_load(src,     AS_RELAXED, AS_AGENT);
      u64 w1 = __hip_atomic_load(src + 1, AS_RELAXED, AS_AGENT);
      u64* dst = (u64*)&h_frag[slot * 8];
      dst[0] = w0; dst[1] = w1;
    }
    // stage x fragments (plain loads -- x is read-only input)
    #pragma unroll
    for (int i = 0; i < 2; ++i){
      int slot = tid + i * 256;
      int kt = slot >> 6, l2 = slot & 63;
      int b = b_base + (l2 & 15), k = kt * 32 + (l2 >> 4) * 8;
      uint4v v = {0u,0u,0u,0u};
      if (!(kt == 7 && (l2 >> 4) == 3)){
        const float* p = x + ((size_t)t * NB + b) * NIN + k;
        float4v u0 = *(const float4v*)p;
        float4v u1 = *(const float4v*)(p + 4);
        v[0] = (unsigned)f2bf(u0[0]) | ((unsigned)f2bf(u0[1]) << 16);
        v[1] = (unsigned)f2bf(u0[2]) | ((unsigned)f2bf(u0[3]) << 16);
        v[2] = (unsigned)f2bf(u1[0]) | ((unsigned)f2bf(u1[1]) << 16);
        v[3] = (unsigned)f2bf(u1[2]) | ((unsigned)f2bf(u1[3]) << 16);
      }
      *(uint4v*)&x_frag[slot * 8] = v;
    }
    if (tid < 16) zpart[tid] = 0.f;
    __syncthreads();

    // P2: MFMA, acc init with bias (all 4 C regs share column j)
    f32x4 acc = {bias, bias, bias, bias};
    #pragma unroll
    for (int kt = 0; kt < 32; ++kt){
      short8 a = *(const short8*)&h_frag[(kt * 64 + l) * 8];
      acc = __builtin_amdgcn_mfma_f32_16x16x32_bf16(a, whh[kt], acc, 0, 0, 0);
    }
    #pragma unroll
    for (int kt = 0; kt < 8; ++kt){
      short8 a = *(const short8*)&x_frag[(kt * 64 + l) * 8];
      acc = __builtin_amdgcn_mfma_f32_16x16x32_bf16(a, wih[kt], acc, 0, 0, 0);
    }

    // P3: tanh, LDS transpose of h_new, z partials
    float hv[4];
    #pragma unroll
    for (int i = 0; i < 4; ++i){
      hv[i] = tanh_fast(acc[i]);
      // C/D layout: row(b) = quad*4 + i, col(j) = n
      h_out[(quad * 4 + i) * 64 + wv * 16 + n] = f2bf(hv[i]);
    }
    float sv[4];
    #pragma unroll
    for (int i = 0; i < 4; ++i) sv[i] = hv[i] * woutj;
    #pragma unroll
    for (int m = 1; m < 16; m <<= 1){
      #pragma unroll
      for (int i = 0; i < 4; ++i) sv[i] += __shfl_xor(sv[i], m, 64);
    }
    if (n == 0){
      #pragma unroll
      for (int i = 0; i < 4; ++i) atomicAdd(&zpart[quad * 4 + i], sv[i]);
    }
    __syncthreads();

    // store h_new tile (one coherent 8B store per thread) + z row
    {
      int r = tid >> 4, c = (tid & 15) * 4;
      u64 v = *(const u64*)&h_out[r * 64 + c];
      __hip_atomic_store((u64*)&hn[(size_t)(b_base + r) * NH + jg * 64 + c],
                         v, AS_RELAXED, AS_AGENT);
    }
    if (tid < 16) atomicAdd(&z[(size_t)t * NB + b_base + tid], zpart[tid]);

    // per-bg barrier: all 16 WGs' h_new stores drained before next step
    target += 16;
    __syncthreads();   // drain this WG's stores
    if (tid == 0){
      __hip_atomic_fetch_add(ctr, 1u, __ATOMIC_RELEASE, AS_AGENT);
      while (__hip_atomic_load(ctr, AS_RELAXED, AS_AGENT) < target)
        __builtin_amdgcn_s_sleep(2);
    }
    __syncthreads();
  }
}

// o_t = sigmoid(z_t + b_out + w_r*o_{t-1} + b_r), o_0 = sigmoid(z_0 + b_out).
// 256 independent chains. Output (B, T) row-major.
__global__ void out_scan_kernel(const float* __restrict__ z,
                                const float* __restrict__ b_out,
                                const float* __restrict__ w_r,
                                const float* __restrict__ b_r,
                                float* __restrict__ out)
{
  int b = threadIdx.x;
  float bo = b_out[0], wr = w_r[0], br = b_r[0];
  float o = 0.f;
  for (int t = 0; t < T_SEQ; ++t){
    float pre = z[(size_t)t * NB + b] + bo;
    if (t > 0) pre += wr * o + br;
    o = 1.0f / (1.0f + __expf(-pre));
    out[(size_t)b * T_SEQ + t] = o;
  }
}

extern "C" void kernel_launch(void* const* d_in, const int* in_sizes, int n_in,
                              void* d_out, int out_size, void* d_ws, size_t ws_size,
                              hipStream_t stream)
{
  (void)in_sizes; (void)n_in; (void)out_size; (void)ws_size;
  const float* x     = (const float*)d_in[0];
  const float* W_ih  = (const float*)d_in[1];
  const float* b_ih  = (const float*)d_in[2];
  const float* W_hh  = (const float*)d_in[3];
  const float* b_hh  = (const float*)d_in[4];
  const float* W_out = (const float*)d_in[5];
  const float* b_out = (const float*)d_in[6];
  const float* w_r   = (const float*)d_in[7];
  const float* b_r   = (const float*)d_in[8];
  float* out = (float*)d_out;

  // ws: h ping-pong (2 x 512 KB bf16) | z (512 KB fp32) | barrier (2 KB)
  unsigned short* hbuf = (unsigned short*)d_ws;
  float* z = (float*)((char*)d_ws + 2 * (size_t)NB * NH * sizeof(unsigned short));
  unsigned int* bar = (unsigned int*)((char*)d_ws
                        + 2 * (size_t)NB * NH * sizeof(unsigned short)
                        + (size_t)T_SEQ * NB * sizeof(float));

  hipMemsetAsync(bar, 0, 16 * 32 * sizeof(unsigned int), stream);

  rnn_scan_kernel<<<dim3(256), dim3(256), 0, stream>>>(
      x, W_ih, b_ih, W_hh, b_hh, W_out, hbuf, z, bar);

  out_scan_kernel<<<dim3(1), dim3(256), 0, stream>>>(z, b_out, w_r, b_r, out);
}

// Round 4
// 2698.756 us; speedup vs baseline: 1.5213x; 1.5213x over previous
//
#include <hip/hip_runtime.h>

#define T_SEQ 512
#define NB    256
#define NIN   248
#define NH    1024

typedef __attribute__((ext_vector_type(8))) short          short8;
typedef __attribute__((ext_vector_type(4))) float          f32x4;
typedef __attribute__((ext_vector_type(4))) unsigned int   uint4v;
typedef __attribute__((ext_vector_type(4))) float          float4v;
typedef unsigned long long u64;

#define AS_RELAXED __ATOMIC_RELAXED
#define AS_AGENT   __HIP_MEMORY_SCOPE_AGENT

__device__ __forceinline__ unsigned short f2bf(float f){
  unsigned int u = __float_as_uint(f);
  u += 0x7FFFu + ((u >> 16) & 1u);     // RNE
  return (unsigned short)(u >> 16);
}

__device__ __forceinline__ float tanh_fast(float v){
  float e = __expf(2.0f * v);          // overflow -> inf -> tanh -> 1 (safe)
  return 1.0f - 2.0f / (e + 1.0f);
}

// Persistent kernel, plain launch. 256 WGs = 16 batch-groups (bg) x 16
// hidden-groups (jg); all blocks co-resident (1 block/CU). Per-bg spin
// barrier with a monotonic counter. ALL barrier/exchange atomics are
// RELAXED agent-scope: release/acquire at agent scope on gfx950 emit
// buffer_wbl2/buffer_inv (full per-XCD L2 writeback/invalidate) -- that
// was the ~6 us/step stall in R3. Relaxed is sufficient because h stores
// are write-through atomics acked at the coherence point before the
// pre-barrier vmcnt(0) drain.
__launch_bounds__(256, 1)
__global__ void rnn_scan_kernel(const float* __restrict__ x,
                                const float* __restrict__ W_ih,
                                const float* __restrict__ b_ih,
                                const float* __restrict__ W_hh,
                                const float* __restrict__ b_hh,
                                const float* __restrict__ W_out,
                                unsigned short* __restrict__ hbuf,
                                float* __restrict__ z,
                                unsigned int* __restrict__ bar)
{
  __shared__ alignas(16) unsigned short h_frag[2048 * 8]; // 32 KB A-fragments
  __shared__ alignas(16) unsigned short x_frag[512 * 8];  //  8 KB x-fragments
  __shared__ alignas(8)  unsigned short h_out[16 * 64];   //  2 KB store-transpose
  __shared__ float z_hist[T_SEQ * 16];                    // 32 KB deferred z partials

  const int tid    = threadIdx.x;
  const int wg     = blockIdx.x;
  const int r16    = wg & 15;
  const int bg     = (r16 & 7) * 2 + (r16 >> 3);  // same-XCD grouping heuristic
  const int jg     = wg >> 4;
  const int b_base = bg * 16;
  const int l      = tid & 63;
  const int wv     = tid >> 6;
  const int n      = l & 15;     // MFMA col (B-operand n / C-D col)
  const int quad   = l >> 4;
  const int j      = jg * 64 + wv * 16 + n;   // this lane's output column

  unsigned short* h0 = hbuf;
  unsigned short* h1 = hbuf + (size_t)NB * NH;
  unsigned int* ctr  = bar + bg * 32;         // one 128B line per batch-group

  // ---- resident B fragments: W_hh^T slice (bf16) in VGPRs ----
  short8 whh[32];
  #pragma unroll
  for (int kt = 0; kt < 32; ++kt){
    const float* p = W_hh + (size_t)j * NH + kt * 32 + quad * 8;
    float4v a = *(const float4v*)p;
    float4v b = *(const float4v*)(p + 4);
    short8 v;
    v[0]=(short)f2bf(a[0]); v[1]=(short)f2bf(a[1]); v[2]=(short)f2bf(a[2]); v[3]=(short)f2bf(a[3]);
    v[4]=(short)f2bf(b[0]); v[5]=(short)f2bf(b[1]); v[6]=(short)f2bf(b[2]); v[7]=(short)f2bf(b[3]);
    whh[kt] = v;
  }
  short8 wih[8];
  #pragma unroll
  for (int kt = 0; kt < 8; ++kt){
    short8 v = {0,0,0,0,0,0,0,0};
    if (!(kt == 7 && quad == 3)){            // k in [248,256) -> zero pad
      const float* p = W_ih + (size_t)j * NIN + kt * 32 + quad * 8;
      float4v a = *(const float4v*)p;
      float4v b = *(const float4v*)(p + 4);
      v[0]=(short)f2bf(a[0]); v[1]=(short)f2bf(a[1]); v[2]=(short)f2bf(a[2]); v[3]=(short)f2bf(a[3]);
      v[4]=(short)f2bf(b[0]); v[5]=(short)f2bf(b[1]); v[6]=(short)f2bf(b[2]); v[7]=(short)f2bf(b[3]);
    }
    wih[kt] = v;
  }
  const float bias  = b_ih[j] + b_hh[j];
  const float woutj = W_out[j];

  // ---- init: z_hist = 0, h0 slice = 0, z global slice = 0 ----
  #pragma unroll
  for (int i = 0; i < 32; ++i) z_hist[tid + i * 256] = 0.f;
  {
    int r = tid >> 4, c = (tid & 15) * 4;
    __hip_atomic_store((u64*)&h0[(size_t)(b_base + r) * NH + jg * 64 + c],
                       0ull, AS_RELAXED, AS_AGENT);
    int tt = jg * 32 + (tid >> 3);
    int bb = (tid & 7) * 2;
    __hip_atomic_store(&z[(size_t)tt * NB + b_base + bb],     0.f, AS_RELAXED, AS_AGENT);
    __hip_atomic_store(&z[(size_t)tt * NB + b_base + bb + 1], 0.f, AS_RELAXED, AS_AGENT);
  }

  // ---- x prefetch slots (t=0) ----
  const int xslot_kt[2] = { tid >> 6, (tid + 256) >> 6 };
  const int xslot_l2[2] = { tid & 63, tid & 63 };
  float4v xr[2][2];
  bool    xvalid[2];
  #pragma unroll
  for (int i = 0; i < 2; ++i){
    int kt = xslot_kt[i], l2 = xslot_l2[i];
    int b = b_base + (l2 & 15), k = kt * 32 + (l2 >> 4) * 8;
    xvalid[i] = !(kt == 7 && (l2 >> 4) == 3);
    if (xvalid[i]){
      const float* p = x + ((size_t)0 * NB + b) * NIN + k;
      xr[i][0] = *(const float4v*)p;
      xr[i][1] = *(const float4v*)(p + 4);
    }
  }

  // ---- per-bg barrier (monotonic counter, RELAXED) ----
  unsigned int target = 16;
  __syncthreads();   // drains init stores (vmcnt(0) before s_barrier)
  if (tid == 0){
    __hip_atomic_fetch_add(ctr, 1u, AS_RELAXED, AS_AGENT);
    while (__hip_atomic_load(ctr, AS_RELAXED, AS_AGENT) < target)
      __builtin_amdgcn_s_sleep(1);
  }
  __syncthreads();

  for (int t = 0; t < T_SEQ; ++t){
    const unsigned short* hp = (t & 1) ? h1 : h0;
    unsigned short*       hn = (t & 1) ? h0 : h1;

    // P1: stage h fragments (coherent 8B loads -> LDS, MFMA A layout)
    #pragma unroll
    for (int i = 0; i < 8; ++i){
      int slot = tid + i * 256;
      int kt = slot >> 6, l2 = slot & 63;
      int b = b_base + (l2 & 15), k = kt * 32 + (l2 >> 4) * 8;
      const u64* src = (const u64*)(hp + (size_t)b * NH + k);
      u64 w0 = __hip_atomic_load(src,     AS_RELAXED, AS_AGENT);
      u64 w1 = __hip_atomic_load(src + 1, AS_RELAXED, AS_AGENT);
      u64* dst = (u64*)&h_frag[slot * 8];
      dst[0] = w0; dst[1] = w1;
    }
    // x fragments from prefetched registers (fp32 -> bf16)
    #pragma unroll
    for (int i = 0; i < 2; ++i){
      int slot = tid + i * 256;
      uint4v v = {0u,0u,0u,0u};
      if (xvalid[i]){
        v[0] = (unsigned)f2bf(xr[i][0][0]) | ((unsigned)f2bf(xr[i][0][1]) << 16);
        v[1] = (unsigned)f2bf(xr[i][0][2]) | ((unsigned)f2bf(xr[i][0][3]) << 16);
        v[2] = (unsigned)f2bf(xr[i][1][0]) | ((unsigned)f2bf(xr[i][1][1]) << 16);
        v[3] = (unsigned)f2bf(xr[i][1][2]) | ((unsigned)f2bf(xr[i][1][3]) << 16);
      }
      *(uint4v*)&x_frag[slot * 8] = v;
    }
    __syncthreads();

    // P2: MFMA, dual accumulators to halve the dependent chain
    f32x4 acc0 = {bias, bias, bias, bias};
    f32x4 acc1 = {0.f, 0.f, 0.f, 0.f};
    #pragma unroll
    for (int kt = 0; kt < 32; kt += 2){
      short8 a0 = *(const short8*)&h_frag[(kt * 64 + l) * 8];
      short8 a1 = *(const short8*)&h_frag[((kt + 1) * 64 + l) * 8];
      acc0 = __builtin_amdgcn_mfma_f32_16x16x32_bf16(a0, whh[kt],     acc0, 0, 0, 0);
      acc1 = __builtin_amdgcn_mfma_f32_16x16x32_bf16(a1, whh[kt + 1], acc1, 0, 0, 0);
    }
    #pragma unroll
    for (int kt = 0; kt < 8; kt += 2){
      short8 a0 = *(const short8*)&x_frag[(kt * 64 + l) * 8];
      short8 a1 = *(const short8*)&x_frag[((kt + 1) * 64 + l) * 8];
      acc0 = __builtin_amdgcn_mfma_f32_16x16x32_bf16(a0, wih[kt],     acc0, 0, 0, 0);
      acc1 = __builtin_amdgcn_mfma_f32_16x16x32_bf16(a1, wih[kt + 1], acc1, 0, 0, 0);
    }

    // prefetch x for t+1 (issues during MFMA drain; overlaps barrier)
    {
      int tn = (t + 1 < T_SEQ) ? t + 1 : t;
      #pragma unroll
      for (int i = 0; i < 2; ++i){
        if (xvalid[i]){
          int kt = xslot_kt[i], l2 = xslot_l2[i];
          int b = b_base + (l2 & 15), k = kt * 32 + (l2 >> 4) * 8;
          const float* p = x + ((size_t)tn * NB + b) * NIN + k;
          xr[i][0] = *(const float4v*)p;
          xr[i][1] = *(const float4v*)(p + 4);
        }
      }
    }

    // P3: tanh, LDS transpose of h_new, z partials -> z_hist (deferred)
    float hv[4];
    #pragma unroll
    for (int i = 0; i < 4; ++i){
      hv[i] = tanh_fast(acc0[i] + acc1[i]);
      // C/D layout: row(b) = quad*4 + i, col(j) = n
      h_out[(quad * 4 + i) * 64 + wv * 16 + n] = f2bf(hv[i]);
    }
    float sv[4];
    #pragma unroll
    for (int i = 0; i < 4; ++i) sv[i] = hv[i] * woutj;
    #pragma unroll
    for (int m = 1; m < 16; m <<= 1){
      #pragma unroll
      for (int i = 0; i < 4; ++i) sv[i] += __shfl_xor(sv[i], m, 64);
    }
    if (n == 0){
      #pragma unroll
      for (int i = 0; i < 4; ++i) atomicAdd(&z_hist[t * 16 + quad * 4 + i], sv[i]);
    }
    __syncthreads();

    // store h_new tile (one coherent 8B store per thread)
    {
      int r = tid >> 4, c = (tid & 15) * 4;
      u64 v = *(const u64*)&h_out[r * 64 + c];
      __hip_atomic_store((u64*)&hn[(size_t)(b_base + r) * NH + jg * 64 + c],
                         v, AS_RELAXED, AS_AGENT);
    }

    // per-bg barrier: vmcnt(0) drain at __syncthreads, then RELAXED arrive+spin
    target += 16;
    __syncthreads();
    if (tid == 0){
      __hip_atomic_fetch_add(ctr, 1u, AS_RELAXED, AS_AGENT);
      while (__hip_atomic_load(ctr, AS_RELAXED, AS_AGENT) < target)
        __builtin_amdgcn_s_sleep(1);
    }
    __syncthreads();
  }

  // ---- bulk z flush (off the critical path) ----
  __syncthreads();
  #pragma unroll
  for (int i = 0; i < 32; ++i){
    int idx = tid + i * 256;
    int tt = idx >> 4, bb = idx & 15;
    atomicAdd(&z[(size_t)tt * NB + b_base + bb], z_hist[idx]);
  }
}

// o_t = sigmoid(z_t + b_out + w_r*o_{t-1} + b_r), o_0 = sigmoid(z_0 + b_out).
// 256 independent chains. Output (B, T) row-major.
__global__ void out_scan_kernel(const float* __restrict__ z,
                                const float* __restrict__ b_out,
                                const float* __restrict__ w_r,
                                const float* __restrict__ b_r,
                                float* __restrict__ out)
{
  int b = threadIdx.x;
  float bo = b_out[0], wr = w_r[0], br = b_r[0];
  float o = 0.f;
  for (int t = 0; t < T_SEQ; ++t){
    float pre = z[(size_t)t * NB + b] + bo;
    if (t > 0) pre += wr * o + br;
    o = 1.0f / (1.0f + __expf(-pre));
    out[(size_t)b * T_SEQ + t] = o;
  }
}

extern "C" void kernel_launch(void* const* d_in, const int* in_sizes, int n_in,
                              void* d_out, int out_size, void* d_ws, size_t ws_size,
                              hipStream_t stream)
{
  (void)in_sizes; (void)n_in; (void)out_size; (void)ws_size;
  const float* x     = (const float*)d_in[0];
  const float* W_ih  = (const float*)d_in[1];
  const float* b_ih  = (const float*)d_in[2];
  const float* W_hh  = (const float*)d_in[3];
  const float* b_hh  = (const float*)d_in[4];
  const float* W_out = (const float*)d_in[5];
  const float* b_out = (const float*)d_in[6];
  const float* w_r   = (const float*)d_in[7];
  const float* b_r   = (const float*)d_in[8];
  float* out = (float*)d_out;

  // ws: h ping-pong (2 x 512 KB bf16) | z (512 KB fp32) | barrier (2 KB)
  unsigned short* hbuf = (unsigned short*)d_ws;
  float* z = (float*)((char*)d_ws + 2 * (size_t)NB * NH * sizeof(unsigned short));
  unsigned int* bar = (unsigned int*)((char*)d_ws
                        + 2 * (size_t)NB * NH * sizeof(unsigned short)
                        + (size_t)T_SEQ * NB * sizeof(float));

  hipMemsetAsync(bar, 0, 16 * 32 * sizeof(unsigned int), stream);

  rnn_scan_kernel<<<dim3(256), dim3(256), 0, stream>>>(
      x, W_ih, b_ih, W_hh, b_hh, W_out, hbuf, z, bar);

  out_scan_kernel<<<dim3(1), dim3(256), 0, stream>>>(z, b_out, w_r, b_r, out);
}